// Round 6
// baseline (114.368 us; speedup 1.0000x reference)
//
#include <hip/hip_runtime.h>
#include <hip/hip_bf16.h>

#define N_NODES 8192
#define F_IN    512
#define F_HID   256
#define ALPHA   0.2f
#define MAXDEG  64

using f32x4 = __attribute__((ext_vector_type(4))) float;
using f16x8 = __attribute__((ext_vector_type(8))) _Float16;
using f16x4 = __attribute__((ext_vector_type(4))) _Float16;

// ---------------------------------------------------------------------------
// Kernel 1: W f32 -> WT fp16 (both layers) + zero the 4 s/t accumulators.
// ---------------------------------------------------------------------------
__global__ void conv_WT(const float* __restrict__ W1, const float* __restrict__ W2,
                        _Float16* __restrict__ W1T, _Float16* __restrict__ W2T,
                        float* __restrict__ stz) {
    int gid = blockIdx.x * blockDim.x + threadIdx.x;
    if (gid < 4 * N_NODES) stz[gid] = 0.0f;

    int t = blockIdx.x;
    const float* W; _Float16* WT; int K, N, kt, nt;
    if (t < 128) { W = W1; WT = W1T; K = 512; N = 256; kt = t & 15; nt = t >> 4; }
    else { t -= 128; W = W2; WT = W2T; K = 256; N = 512; kt = t & 7; nt = t >> 3; }
    __shared__ float Ws[32][33];
    const int tx = threadIdx.x & 31, ty = threadIdx.x >> 5;  // 32 x 8
    #pragma unroll
    for (int i = 0; i < 4; ++i)
        Ws[ty + 8 * i][tx] = W[(size_t)(kt * 32 + ty + 8 * i) * N + nt * 32 + tx];
    __syncthreads();
    #pragma unroll
    for (int i = 0; i < 4; ++i)
        WT[(size_t)(nt * 32 + ty + 8 * i) * K + kt * 32 + tx] = (_Float16)Ws[tx][ty + 8 * i];
}

// ---------------------------------------------------------------------------
// CSR row scan: one wave per adjacency row, 2 x float4 nontemporal per iter.
// ---------------------------------------------------------------------------
__device__ inline void csr_row(const float* __restrict__ adj, int* __restrict__ cols,
                               int* __restrict__ cnt, int row, int lane) {
    const f32x4* arow = (const f32x4*)(adj + (size_t)row * N_NODES);
    int* crow = cols + (size_t)row * MAXDEG;
    int count = 0;
    const unsigned long long mlt = (1ULL << lane) - 1ULL;
    for (int base = 0; base < N_NODES; base += 512) {
        f32x4 v0 = __builtin_nontemporal_load(&arow[(base >> 2) + lane]);
        f32x4 v1 = __builtin_nontemporal_load(&arow[(base >> 2) + 64 + lane]);
        unsigned long long b0 = __ballot(v0[0] > 0.0f);
        unsigned long long b1 = __ballot(v0[1] > 0.0f);
        unsigned long long b2 = __ballot(v0[2] > 0.0f);
        unsigned long long b3 = __ballot(v0[3] > 0.0f);
        unsigned long long b4 = __ballot(v1[0] > 0.0f);
        unsigned long long b5 = __ballot(v1[1] > 0.0f);
        unsigned long long b6 = __ballot(v1[2] > 0.0f);
        unsigned long long b7 = __ballot(v1[3] > 0.0f);
        int o = count + __popcll(b0 & mlt) + __popcll(b1 & mlt)
                      + __popcll(b2 & mlt) + __popcll(b3 & mlt);
        int c0 = base + (lane << 2);
        if (v0[0] > 0.0f) { if (o < MAXDEG) crow[o] = c0;     o++; }
        if (v0[1] > 0.0f) { if (o < MAXDEG) crow[o] = c0 + 1; o++; }
        if (v0[2] > 0.0f) { if (o < MAXDEG) crow[o] = c0 + 2; o++; }
        if (v0[3] > 0.0f) { if (o < MAXDEG) crow[o] = c0 + 3; o++; }
        count += __popcll(b0) + __popcll(b1) + __popcll(b2) + __popcll(b3);
        o = count + __popcll(b4 & mlt) + __popcll(b5 & mlt)
                  + __popcll(b6 & mlt) + __popcll(b7 & mlt);
        int c1 = base + 256 + (lane << 2);
        if (v1[0] > 0.0f) { if (o < MAXDEG) crow[o] = c1;     o++; }
        if (v1[1] > 0.0f) { if (o < MAXDEG) crow[o] = c1 + 1; o++; }
        if (v1[2] > 0.0f) { if (o < MAXDEG) crow[o] = c1 + 2; o++; }
        if (v1[3] > 0.0f) { if (o < MAXDEG) crow[o] = c1 + 3; o++; }
        count += __popcll(b4) + __popcll(b5) + __popcll(b6) + __popcll(b7);
    }
    if (lane == 0) cnt[row] = count > MAXDEG ? MAXDEG : count;
}

// ---------------------------------------------------------------------------
// GEMM1 tile: Wh1[64x64] fp16 = x(f32->f16, NT loads) @ W1T; epilogue adds
// this tile's contribution to s1/t1 (16-lane reduce + atomicAdd).
// ---------------------------------------------------------------------------
__device__ inline void gemm1_tile(const float* __restrict__ x,
                                  const _Float16* __restrict__ W1T,
                                  _Float16* __restrict__ Wh1,
                                  const float* __restrict__ a1,
                                  float* __restrict__ s1, float* __restrict__ t1,
                                  int brow, int bcol) {
    const int LDT = 72;
    __shared__ _Float16 As[64 * LDT];
    __shared__ _Float16 Bs[64 * LDT];
    const int tid = threadIdx.x;
    const int wid = tid >> 6, lane = tid & 63;
    const int wr = (wid >> 1) * 32, wc = (wid & 1) * 32;
    const int sr = tid >> 3, skg = (tid & 7) * 8;

    f32x4 acc[2][2];
    #pragma unroll
    for (int m = 0; m < 2; ++m)
        #pragma unroll
        for (int n = 0; n < 2; ++n) acc[m][n] = f32x4{0.f, 0.f, 0.f, 0.f};

    for (int k0 = 0; k0 < F_IN; k0 += 64) {
        #pragma unroll
        for (int i = 0; i < 2; ++i) {
            int r = sr + i * 32;
            const f32x4* src = (const f32x4*)(x + (size_t)(brow + r) * F_IN + k0 + skg);
            f32x4 a0 = __builtin_nontemporal_load(src);
            f32x4 a1v = __builtin_nontemporal_load(src + 1);
            f16x8 av;
            #pragma unroll
            for (int j = 0; j < 4; ++j) { av[j] = (_Float16)a0[j]; av[4 + j] = (_Float16)a1v[j]; }
            *(f16x8*)&As[r * LDT + skg] = av;
            *(f16x8*)&Bs[r * LDT + skg] = *(const f16x8*)&W1T[(size_t)(bcol + r) * F_IN + k0 + skg];
        }
        __syncthreads();
        #pragma unroll
        for (int ks = 0; ks < 2; ++ks) {
            const int kb = ks * 32 + (lane >> 4) * 8;
            f16x8 af[2], bfr[2];
            #pragma unroll
            for (int m = 0; m < 2; ++m)
                af[m] = *(const f16x8*)&As[(wr + m * 16 + (lane & 15)) * LDT + kb];
            #pragma unroll
            for (int n = 0; n < 2; ++n)
                bfr[n] = *(const f16x8*)&Bs[(wc + n * 16 + (lane & 15)) * LDT + kb];
            #pragma unroll
            for (int m = 0; m < 2; ++m)
                #pragma unroll
                for (int n = 0; n < 2; ++n)
                    acc[m][n] = __builtin_amdgcn_mfma_f32_16x16x32_f16(
                        af[m], bfr[n], acc[m][n], 0, 0, 0);
        }
        __syncthreads();
    }
    const int c0 = bcol + wc + (lane & 15);
    float as0 = a1[c0],         as1 = a1[c0 + 16];
    float at0 = a1[F_HID + c0], at1 = a1[F_HID + c0 + 16];
    #pragma unroll
    for (int m = 0; m < 2; ++m) {
        #pragma unroll
        for (int j = 0; j < 4; ++j) {
            float vs = acc[m][0][j] * as0 + acc[m][1][j] * as1;
            float vt = acc[m][0][j] * at0 + acc[m][1][j] * at1;
            #pragma unroll
            for (int off = 1; off < 16; off <<= 1) {
                vs += __shfl_xor(vs, off);
                vt += __shfl_xor(vt, off);
            }
            if ((lane & 15) == 0) {
                int row = brow + wr + m * 16 + ((lane >> 4) << 2) + j;
                atomicAdd(s1 + row, vs);
                atomicAdd(t1 + row, vt);
            }
        }
        #pragma unroll
        for (int n = 0; n < 2; ++n) {
            int row = brow + wr + m * 16 + ((lane >> 4) << 2);
            int col = bcol + wc + n * 16 + (lane & 15);
            #pragma unroll
            for (int j = 0; j < 4; ++j)
                Wh1[(size_t)(row + j) * F_HID + col] = (_Float16)acc[m][n][j];
        }
    }
}

// ---------------------------------------------------------------------------
// Merged: csr scan (HBM-bound) co-scheduled with GEMM1+st1 (MFMA-bound).
// ---------------------------------------------------------------------------
__global__ __launch_bounds__(256)
void csr_and_gemm1(const float* __restrict__ adj, int* __restrict__ cols,
                   int* __restrict__ cnt, const float* __restrict__ x,
                   const _Float16* __restrict__ W1T, _Float16* __restrict__ Wh1,
                   const float* __restrict__ a1,
                   float* __restrict__ s1, float* __restrict__ t1) {
    const int bid = blockIdx.x;
    const int g = bid / 5, r = bid % 5;
    if (r == 0) {
        gemm1_tile(x, W1T, Wh1, a1, s1, t1, (g >> 2) * 64, (g & 3) * 64);
    } else {
        const int cb = g * 4 + (r - 1);                 // [0, 2048)
        const int row = cb * 4 + (threadIdx.x >> 6);
        csr_row(adj, cols, cnt, row, threadIdx.x & 63);
    }
}

// ---------------------------------------------------------------------------
// GEMM2: Wh2[8192,512] fp16 = enc16 @ W2T. BM=128, BN=64, B panel resident
// in LDS (staged once); A restaged per 64-k step; epilogue adds to s2/t2.
// ---------------------------------------------------------------------------
__global__ __launch_bounds__(256)
void gemm2_f16(const _Float16* __restrict__ A, const _Float16* __restrict__ BT,
               _Float16* __restrict__ C, const float* __restrict__ a2,
               float* __restrict__ s2, float* __restrict__ t2) {
    const int LDT = 72, LDB = 264;
    __shared__ _Float16 As[128 * LDT];     // 18.4 KB
    __shared__ _Float16 Bs[64 * LDB];      // 33.8 KB
    const int tid = threadIdx.x;
    const int wid = tid >> 6, lane = tid & 63;
    const int brow = (blockIdx.x >> 3) * 128;
    const int bcol = (blockIdx.x & 7) * 64;
    const int wr = (wid >> 1) * 64, wc = (wid & 1) * 32;

    // stage whole B panel once: 64 rows x 256 k
    #pragma unroll
    for (int i = 0; i < 8; ++i) {
        int id = tid + i * 256;
        int r = id >> 5, kc = (id & 31) * 8;
        *(f16x8*)&Bs[r * LDB + kc] = *(const f16x8*)&BT[(size_t)(bcol + r) * F_HID + kc];
    }

    f32x4 acc[4][2];
    #pragma unroll
    for (int m = 0; m < 4; ++m)
        #pragma unroll
        for (int n = 0; n < 2; ++n) acc[m][n] = f32x4{0.f, 0.f, 0.f, 0.f};

    for (int k0 = 0; k0 < F_HID; k0 += 64) {
        #pragma unroll
        for (int i = 0; i < 4; ++i) {
            int id = tid + i * 256;
            int r = id >> 3, kc = (id & 7) * 8;
            *(f16x8*)&As[r * LDT + kc] = *(const f16x8*)&A[(size_t)(brow + r) * F_HID + k0 + kc];
        }
        __syncthreads();
        #pragma unroll
        for (int ks = 0; ks < 2; ++ks) {
            const int kb = ks * 32 + (lane >> 4) * 8;
            f16x8 af[4], bfr[2];
            #pragma unroll
            for (int m = 0; m < 4; ++m)
                af[m] = *(const f16x8*)&As[(wr + m * 16 + (lane & 15)) * LDT + kb];
            #pragma unroll
            for (int n = 0; n < 2; ++n)
                bfr[n] = *(const f16x8*)&Bs[(wc + n * 16 + (lane & 15)) * LDB + k0 + kb];
            #pragma unroll
            for (int m = 0; m < 4; ++m)
                #pragma unroll
                for (int n = 0; n < 2; ++n)
                    acc[m][n] = __builtin_amdgcn_mfma_f32_16x16x32_f16(
                        af[m], bfr[n], acc[m][n], 0, 0, 0);
        }
        __syncthreads();
    }
    const int c0 = bcol + wc + (lane & 15);
    float as0 = a2[c0],        as1 = a2[c0 + 16];
    float at0 = a2[F_IN + c0], at1 = a2[F_IN + c0 + 16];
    #pragma unroll
    for (int m = 0; m < 4; ++m) {
        #pragma unroll
        for (int j = 0; j < 4; ++j) {
            float vs = acc[m][0][j] * as0 + acc[m][1][j] * as1;
            float vt = acc[m][0][j] * at0 + acc[m][1][j] * at1;
            #pragma unroll
            for (int off = 1; off < 16; off <<= 1) {
                vs += __shfl_xor(vs, off);
                vt += __shfl_xor(vt, off);
            }
            if ((lane & 15) == 0) {
                int row = brow + wr + m * 16 + ((lane >> 4) << 2) + j;
                atomicAdd(s2 + row, vs);
                atomicAdd(t2 + row, vt);
            }
        }
        #pragma unroll
        for (int n = 0; n < 2; ++n) {
            int row = brow + wr + m * 16 + ((lane >> 4) << 2);
            int col = bcol + wc + n * 16 + (lane & 15);
            #pragma unroll
            for (int j = 0; j < 4; ++j)
                C[(size_t)(row + j) * F_IN + col] = (_Float16)acc[m][n][j];
        }
    }
}

// ---------------------------------------------------------------------------
// Masked softmax + aggregate + ELU. Wave per row, fp16 gathers, unroll-8.
// NT stores for f32 outputs (stream-once).
// ---------------------------------------------------------------------------
template<int F>
__global__ void aggregate16(const _Float16* __restrict__ Wh,
                            const int* __restrict__ cols, const int* __restrict__ cnt,
                            const float* __restrict__ s, const float* __restrict__ t,
                            float* __restrict__ out, _Float16* __restrict__ out16) {
    const int EL = F / 64;
    const int wid = threadIdx.x >> 6, lane = threadIdx.x & 63;
    const int row = blockIdx.x * 4 + wid;
    const int deg = cnt[row];
    __shared__ float pS[4][64];
    __shared__ int jS[4][64];
    int j = 0;
    float ev = -1e30f;
    if (lane < deg) {
        j = cols[(size_t)row * MAXDEG + lane];
        float z = s[row] + t[j];
        ev = z > 0.0f ? z : ALPHA * z;
    }
    float m = ev;
    #pragma unroll
    for (int off = 32; off > 0; off >>= 1) m = fmaxf(m, __shfl_xor(m, off));
    float ex = (lane < deg) ? __expf(ev - m) : 0.0f;
    float sum = ex;
    #pragma unroll
    for (int off = 32; off > 0; off >>= 1) sum += __shfl_xor(sum, off);
    pS[wid][lane] = ex / sum;
    jS[wid][lane] = j;
    __syncthreads();

    float acc[EL] = {};
    const size_t lo = (size_t)lane * EL;
    int d = 0;
    for (; d + 8 <= deg; d += 8) {
        float p[8]; const _Float16* w[8];
        #pragma unroll
        for (int q = 0; q < 8; ++q) {
            p[q] = pS[wid][d + q];
            w[q] = Wh + (size_t)jS[wid][d + q] * F + lo;
        }
        if constexpr (EL == 8) {
            f16x8 v[8];
            #pragma unroll
            for (int q = 0; q < 8; ++q) v[q] = *(const f16x8*)w[q];
            #pragma unroll
            for (int jj = 0; jj < 8; ++jj) {
                float a = 0.f;
                #pragma unroll
                for (int q = 0; q < 8; ++q) a += p[q] * (float)v[q][jj];
                acc[jj] += a;
            }
        } else {
            f16x4 v[8];
            #pragma unroll
            for (int q = 0; q < 8; ++q) v[q] = *(const f16x4*)w[q];
            #pragma unroll
            for (int jj = 0; jj < 4; ++jj) {
                float a = 0.f;
                #pragma unroll
                for (int q = 0; q < 8; ++q) a += p[q] * (float)v[q][jj];
                acc[jj] += a;
            }
        }
    }
    for (; d + 4 <= deg; d += 4) {
        float p0 = pS[wid][d],     p1 = pS[wid][d + 1];
        float p2 = pS[wid][d + 2], p3 = pS[wid][d + 3];
        const _Float16* w0 = Wh + (size_t)jS[wid][d] * F + lo;
        const _Float16* w1 = Wh + (size_t)jS[wid][d + 1] * F + lo;
        const _Float16* w2 = Wh + (size_t)jS[wid][d + 2] * F + lo;
        const _Float16* w3 = Wh + (size_t)jS[wid][d + 3] * F + lo;
        if constexpr (EL == 8) {
            f16x8 v0 = *(const f16x8*)w0, v1 = *(const f16x8*)w1;
            f16x8 v2 = *(const f16x8*)w2, v3 = *(const f16x8*)w3;
            #pragma unroll
            for (int jj = 0; jj < 8; ++jj)
                acc[jj] += p0 * (float)v0[jj] + p1 * (float)v1[jj]
                         + p2 * (float)v2[jj] + p3 * (float)v3[jj];
        } else {
            f16x4 v0 = *(const f16x4*)w0, v1 = *(const f16x4*)w1;
            f16x4 v2 = *(const f16x4*)w2, v3 = *(const f16x4*)w3;
            #pragma unroll
            for (int jj = 0; jj < 4; ++jj)
                acc[jj] += p0 * (float)v0[jj] + p1 * (float)v1[jj]
                         + p2 * (float)v2[jj] + p3 * (float)v3[jj];
        }
    }
    for (; d < deg; ++d) {
        float p = pS[wid][d];
        const _Float16* wr = Wh + (size_t)jS[wid][d] * F + lo;
        if constexpr (EL == 8) {
            f16x8 w = *(const f16x8*)wr;
            #pragma unroll
            for (int jj = 0; jj < 8; ++jj) acc[jj] += p * (float)w[jj];
        } else {
            f16x4 w = *(const f16x4*)wr;
            #pragma unroll
            for (int jj = 0; jj < 4; ++jj) acc[jj] += p * (float)w[jj];
        }
    }
    #pragma unroll
    for (int c = 0; c < EL / 4; ++c) {
        f32x4 o; f16x4 h;
        #pragma unroll
        for (int jj = 0; jj < 4; ++jj) {
            float v = acc[c * 4 + jj];
            float e = v > 0.0f ? v : (__expf(v) - 1.0f);
            o[jj] = e; h[jj] = (_Float16)e;
        }
        __builtin_nontemporal_store(o, (f32x4*)(out + (size_t)row * F + lo + c * 4));
        if (out16)
            *(f16x4*)(out16 + (size_t)row * F + lo + c * 4) = h;
    }
}

// ---------------------------------------------------------------------------
extern "C" void kernel_launch(void* const* d_in, const int* in_sizes, int n_in,
                              void* d_out, int out_size, void* d_ws, size_t ws_size,
                              hipStream_t stream) {
    (void)in_sizes; (void)n_in; (void)out_size; (void)ws_size;
    const float* x   = (const float*)d_in[0];
    const float* adj = (const float*)d_in[1];
    const float* W1  = (const float*)d_in[2];
    const float* a1  = (const float*)d_in[3];
    const float* W2  = (const float*)d_in[4];
    const float* a2  = (const float*)d_in[5];

    float* dec = (float*)d_out;                           // [8192, 512] f32
    float* enc = dec + (size_t)N_NODES * F_IN;            // [8192, 256] f32

    int*      cols  = (int*)d_ws;                         // 8192*64
    int*      cnt   = cols + (size_t)N_NODES * MAXDEG;    // 8192
    float*    s1    = (float*)(cnt + N_NODES);            // 8192
    float*    t1    = s1 + N_NODES;                       // 8192
    float*    s2    = t1 + N_NODES;                       // 8192
    float*    t2    = s2 + N_NODES;                       // 8192
    _Float16* Wh1   = (_Float16*)(t2 + N_NODES);          // 8192*256 fp16
    _Float16* Wh2   = Wh1 + (size_t)N_NODES * F_HID;      // 8192*512 fp16
    _Float16* enc16 = Wh2 + (size_t)N_NODES * F_IN;       // 8192*256 fp16
    _Float16* W1T   = enc16 + (size_t)N_NODES * F_HID;    // 256*512 fp16
    _Float16* W2T   = W1T + (size_t)F_HID * F_IN;         // 512*256 fp16

    // 1. W transposes + zero s/t accumulators
    conv_WT<<<256, 256, 0, stream>>>(W1, W2, W1T, W2T, s1);

    // 2. csr scan (HBM, NT) overlapped with layer-1 GEMM + st1 epilogue
    csr_and_gemm1<<<2560, 256, 0, stream>>>(adj, cols, cnt, x, W1T, Wh1, a1, s1, t1);

    // 3. layer-1 attention
    aggregate16<F_HID><<<N_NODES / 4, 256, 0, stream>>>(Wh1, cols, cnt, s1, t1, enc, enc16);

    // 4. layer-2 GEMM + st2 epilogue
    gemm2_f16<<<512, 256, 0, stream>>>(enc16, W2T, Wh2, a2, s2, t2);

    // 5. layer-2 attention
    aggregate16<F_IN><<<N_NODES / 4, 256, 0, stream>>>(Wh2, cols, cnt, s2, t2, dec, (_Float16*)nullptr);
}

// Round 7
// 107.967 us; speedup vs baseline: 1.0593x; 1.0593x over previous
//
#include <hip/hip_runtime.h>
#include <hip/hip_bf16.h>

#define N_NODES 8192
#define F_IN    512
#define F_HID   256
#define ALPHA   0.2f
#define MAXDEG  64

using f32x4 = __attribute__((ext_vector_type(4))) float;
using f16x8 = __attribute__((ext_vector_type(8))) _Float16;
using f16x4 = __attribute__((ext_vector_type(4))) _Float16;

// ---------------------------------------------------------------------------
// Kernel 1: W f32 -> WT fp16 (both layers) + zero s1/t1 + w2s/w2t = W2 @ a2.
// ---------------------------------------------------------------------------
__global__ void conv_WT(const float* __restrict__ W1, const float* __restrict__ W2,
                        _Float16* __restrict__ W1T, _Float16* __restrict__ W2T,
                        const float* __restrict__ a2,
                        float* __restrict__ w2s, float* __restrict__ w2t,
                        float* __restrict__ stz) {
    const int tid = threadIdx.x;
    int gid = blockIdx.x * 256 + tid;
    if (gid < 2 * N_NODES) stz[gid] = 0.0f;    // zero s1,t1

    if (blockIdx.x >= 256) {
        // w2s[k] = W2[k,:] . a2[0:512], w2t[k] = W2[k,:] . a2[512:1024]
        const int r = (blockIdx.x - 256) * 64 + (tid >> 2);   // 64 rows/block
        const int q = tid & 3;                                // 4 thr/row
        float ss = 0.f, tt = 0.f;
        for (int n = q * 4; n < F_IN; n += 16) {
            f32x4 w  = *(const f32x4*)&W2[(size_t)r * F_IN + n];
            f32x4 as = *(const f32x4*)&a2[n];
            f32x4 at = *(const f32x4*)&a2[F_IN + n];
            #pragma unroll
            for (int j = 0; j < 4; ++j) { ss += w[j] * as[j]; tt += w[j] * at[j]; }
        }
        ss += __shfl_xor(ss, 1); ss += __shfl_xor(ss, 2);
        tt += __shfl_xor(tt, 1); tt += __shfl_xor(tt, 2);
        if (q == 0) { w2s[r] = ss; w2t[r] = tt; }
        return;
    }

    int t = blockIdx.x;
    const float* W; _Float16* WT; int K, N, kt, nt;
    if (t < 128) { W = W1; WT = W1T; K = 512; N = 256; kt = t & 15; nt = t >> 4; }
    else { t -= 128; W = W2; WT = W2T; K = 256; N = 512; kt = t & 7; nt = t >> 3; }
    __shared__ float Ws[32][33];
    const int tx = tid & 31, ty = tid >> 5;  // 32 x 8
    #pragma unroll
    for (int i = 0; i < 4; ++i)
        Ws[ty + 8 * i][tx] = W[(size_t)(kt * 32 + ty + 8 * i) * N + nt * 32 + tx];
    __syncthreads();
    #pragma unroll
    for (int i = 0; i < 4; ++i)
        WT[(size_t)(nt * 32 + ty + 8 * i) * K + kt * 32 + tx] = (_Float16)Ws[tx][ty + 8 * i];
}

// ---------------------------------------------------------------------------
// CSR row scan: one wave per adjacency row, 2 x f32x4 nontemporal per iter.
// ---------------------------------------------------------------------------
__device__ inline void csr_row(const float* __restrict__ adj, int* __restrict__ cols,
                               int* __restrict__ cnt, int row, int lane) {
    const f32x4* arow = (const f32x4*)(adj + (size_t)row * N_NODES);
    int* crow = cols + (size_t)row * MAXDEG;
    int count = 0;
    const unsigned long long mlt = (1ULL << lane) - 1ULL;
    for (int base = 0; base < N_NODES; base += 512) {
        f32x4 v0 = __builtin_nontemporal_load(&arow[(base >> 2) + lane]);
        f32x4 v1 = __builtin_nontemporal_load(&arow[(base >> 2) + 64 + lane]);
        unsigned long long b0 = __ballot(v0[0] > 0.0f);
        unsigned long long b1 = __ballot(v0[1] > 0.0f);
        unsigned long long b2 = __ballot(v0[2] > 0.0f);
        unsigned long long b3 = __ballot(v0[3] > 0.0f);
        unsigned long long b4 = __ballot(v1[0] > 0.0f);
        unsigned long long b5 = __ballot(v1[1] > 0.0f);
        unsigned long long b6 = __ballot(v1[2] > 0.0f);
        unsigned long long b7 = __ballot(v1[3] > 0.0f);
        int o = count + __popcll(b0 & mlt) + __popcll(b1 & mlt)
                      + __popcll(b2 & mlt) + __popcll(b3 & mlt);
        int c0 = base + (lane << 2);
        if (v0[0] > 0.0f) { if (o < MAXDEG) crow[o] = c0;     o++; }
        if (v0[1] > 0.0f) { if (o < MAXDEG) crow[o] = c0 + 1; o++; }
        if (v0[2] > 0.0f) { if (o < MAXDEG) crow[o] = c0 + 2; o++; }
        if (v0[3] > 0.0f) { if (o < MAXDEG) crow[o] = c0 + 3; o++; }
        count += __popcll(b0) + __popcll(b1) + __popcll(b2) + __popcll(b3);
        o = count + __popcll(b4 & mlt) + __popcll(b5 & mlt)
                  + __popcll(b6 & mlt) + __popcll(b7 & mlt);
        int c1 = base + 256 + (lane << 2);
        if (v1[0] > 0.0f) { if (o < MAXDEG) crow[o] = c1;     o++; }
        if (v1[1] > 0.0f) { if (o < MAXDEG) crow[o] = c1 + 1; o++; }
        if (v1[2] > 0.0f) { if (o < MAXDEG) crow[o] = c1 + 2; o++; }
        if (v1[3] > 0.0f) { if (o < MAXDEG) crow[o] = c1 + 3; o++; }
        count += __popcll(b4) + __popcll(b5) + __popcll(b6) + __popcll(b7);
    }
    if (lane == 0) cnt[row] = count > MAXDEG ? MAXDEG : count;
}

// ---------------------------------------------------------------------------
// GEMM1 tile: Wh1[64x64] fp16 = x(f32->f16) @ W1T; epilogue atomics s1/t1.
// ---------------------------------------------------------------------------
__device__ inline void gemm1_tile(const float* __restrict__ x,
                                  const _Float16* __restrict__ W1T,
                                  _Float16* __restrict__ Wh1,
                                  const float* __restrict__ a1,
                                  float* __restrict__ s1, float* __restrict__ t1,
                                  int brow, int bcol) {
    const int LDT = 72;
    __shared__ _Float16 As[64 * LDT];
    __shared__ _Float16 Bs[64 * LDT];
    const int tid = threadIdx.x;
    const int wid = tid >> 6, lane = tid & 63;
    const int wr = (wid >> 1) * 32, wc = (wid & 1) * 32;
    const int sr = tid >> 3, skg = (tid & 7) * 8;

    f32x4 acc[2][2];
    #pragma unroll
    for (int m = 0; m < 2; ++m)
        #pragma unroll
        for (int n = 0; n < 2; ++n) acc[m][n] = f32x4{0.f, 0.f, 0.f, 0.f};

    for (int k0 = 0; k0 < F_IN; k0 += 64) {
        #pragma unroll
        for (int i = 0; i < 2; ++i) {
            int r = sr + i * 32;
            const f32x4* src = (const f32x4*)(x + (size_t)(brow + r) * F_IN + k0 + skg);
            f32x4 a0 = __builtin_nontemporal_load(src);
            f32x4 a1v = __builtin_nontemporal_load(src + 1);
            f16x8 av;
            #pragma unroll
            for (int j = 0; j < 4; ++j) { av[j] = (_Float16)a0[j]; av[4 + j] = (_Float16)a1v[j]; }
            *(f16x8*)&As[r * LDT + skg] = av;
            *(f16x8*)&Bs[r * LDT + skg] = *(const f16x8*)&W1T[(size_t)(bcol + r) * F_IN + k0 + skg];
        }
        __syncthreads();
        #pragma unroll
        for (int ks = 0; ks < 2; ++ks) {
            const int kb = ks * 32 + (lane >> 4) * 8;
            f16x8 af[2], bfr[2];
            #pragma unroll
            for (int m = 0; m < 2; ++m)
                af[m] = *(const f16x8*)&As[(wr + m * 16 + (lane & 15)) * LDT + kb];
            #pragma unroll
            for (int n = 0; n < 2; ++n)
                bfr[n] = *(const f16x8*)&Bs[(wc + n * 16 + (lane & 15)) * LDT + kb];
            #pragma unroll
            for (int m = 0; m < 2; ++m)
                #pragma unroll
                for (int n = 0; n < 2; ++n)
                    acc[m][n] = __builtin_amdgcn_mfma_f32_16x16x32_f16(
                        af[m], bfr[n], acc[m][n], 0, 0, 0);
        }
        __syncthreads();
    }
    const int c0 = bcol + wc + (lane & 15);
    float as0 = a1[c0],         as1 = a1[c0 + 16];
    float at0 = a1[F_HID + c0], at1 = a1[F_HID + c0 + 16];
    #pragma unroll
    for (int m = 0; m < 2; ++m) {
        #pragma unroll
        for (int j = 0; j < 4; ++j) {
            float vs = acc[m][0][j] * as0 + acc[m][1][j] * as1;
            float vt = acc[m][0][j] * at0 + acc[m][1][j] * at1;
            #pragma unroll
            for (int off = 1; off < 16; off <<= 1) {
                vs += __shfl_xor(vs, off);
                vt += __shfl_xor(vt, off);
            }
            if ((lane & 15) == 0) {
                int row = brow + wr + m * 16 + ((lane >> 4) << 2) + j;
                atomicAdd(s1 + row, vs);
                atomicAdd(t1 + row, vt);
            }
        }
        #pragma unroll
        for (int n = 0; n < 2; ++n) {
            int row = brow + wr + m * 16 + ((lane >> 4) << 2);
            int col = bcol + wc + n * 16 + (lane & 15);
            #pragma unroll
            for (int j = 0; j < 4; ++j)
                Wh1[(size_t)(row + j) * F_HID + col] = (_Float16)acc[m][n][j];
        }
    }
}

// ---------------------------------------------------------------------------
// Merged: csr scan (HBM-bound) co-scheduled with GEMM1+st1 (MFMA-bound).
// ---------------------------------------------------------------------------
__global__ __launch_bounds__(256)
void csr_and_gemm1(const float* __restrict__ adj, int* __restrict__ cols,
                   int* __restrict__ cnt, const float* __restrict__ x,
                   const _Float16* __restrict__ W1T, _Float16* __restrict__ Wh1,
                   const float* __restrict__ a1,
                   float* __restrict__ s1, float* __restrict__ t1) {
    const int bid = blockIdx.x;
    const int g = bid / 5, r = bid % 5;
    if (r == 0) {
        gemm1_tile(x, W1T, Wh1, a1, s1, t1, (g >> 2) * 64, (g & 3) * 64);
    } else {
        const int cb = g * 4 + (r - 1);                 // [0, 2048)
        const int row = cb * 4 + (threadIdx.x >> 6);
        csr_row(adj, cols, cnt, row, threadIdx.x & 63);
    }
}

// ---------------------------------------------------------------------------
// Layer-1 aggregate: softmax(s1,t1) over neighbors, gather Wh1 (fp16),
// ELU, write enc (f32 NT) + enc16; epilogue s2/t2 = enc_row . w2s/w2t.
// Wave per row, F = 256, EL = 4.
// ---------------------------------------------------------------------------
__global__ void aggregate_l1(const _Float16* __restrict__ Wh,
                             const int* __restrict__ cols, const int* __restrict__ cnt,
                             const float* __restrict__ s, const float* __restrict__ t,
                             const float* __restrict__ w2s, const float* __restrict__ w2t,
                             float* __restrict__ enc, _Float16* __restrict__ enc16,
                             float* __restrict__ s2, float* __restrict__ t2) {
    const int wid = threadIdx.x >> 6, lane = threadIdx.x & 63;
    const int row = blockIdx.x * 4 + wid;
    const int deg = cnt[row];
    __shared__ float pS[4][64];
    __shared__ int jS[4][64];
    int j = 0;
    float ev = -1e30f;
    if (lane < deg) {
        j = cols[(size_t)row * MAXDEG + lane];
        float z = s[row] + t[j];
        ev = z > 0.0f ? z : ALPHA * z;
    }
    float m = ev;
    #pragma unroll
    for (int off = 32; off > 0; off >>= 1) m = fmaxf(m, __shfl_xor(m, off));
    float ex = (lane < deg) ? __expf(ev - m) : 0.0f;
    float sum = ex;
    #pragma unroll
    for (int off = 32; off > 0; off >>= 1) sum += __shfl_xor(sum, off);
    pS[wid][lane] = ex / sum;
    jS[wid][lane] = j;
    __syncthreads();

    float acc[4] = {};
    const size_t lo = (size_t)lane * 4;
    int d = 0;
    for (; d + 4 <= deg; d += 4) {
        float p0 = pS[wid][d],     p1 = pS[wid][d + 1];
        float p2 = pS[wid][d + 2], p3 = pS[wid][d + 3];
        f16x4 v0 = *(const f16x4*)(Wh + (size_t)jS[wid][d] * F_HID + lo);
        f16x4 v1 = *(const f16x4*)(Wh + (size_t)jS[wid][d + 1] * F_HID + lo);
        f16x4 v2 = *(const f16x4*)(Wh + (size_t)jS[wid][d + 2] * F_HID + lo);
        f16x4 v3 = *(const f16x4*)(Wh + (size_t)jS[wid][d + 3] * F_HID + lo);
        #pragma unroll
        for (int jj = 0; jj < 4; ++jj)
            acc[jj] += p0 * (float)v0[jj] + p1 * (float)v1[jj]
                     + p2 * (float)v2[jj] + p3 * (float)v3[jj];
    }
    for (; d < deg; ++d) {
        float p = pS[wid][d];
        f16x4 w = *(const f16x4*)(Wh + (size_t)jS[wid][d] * F_HID + lo);
        #pragma unroll
        for (int jj = 0; jj < 4; ++jj) acc[jj] += p * (float)w[jj];
    }
    f32x4 o; f16x4 h;
    #pragma unroll
    for (int jj = 0; jj < 4; ++jj) {
        float v = acc[jj];
        float e = v > 0.0f ? v : (__expf(v) - 1.0f);
        o[jj] = e; h[jj] = (_Float16)e;
    }
    __builtin_nontemporal_store(o, (f32x4*)(enc + (size_t)row * F_HID + lo));
    *(f16x4*)(enc16 + (size_t)row * F_HID + lo) = h;

    // epilogue: s2[row] = enc_row . w2s, t2[row] = enc_row . w2t
    f32x4 ws = *(const f32x4*)(w2s + lo);
    f32x4 wt = *(const f32x4*)(w2t + lo);
    float ps = 0.f, pt = 0.f;
    #pragma unroll
    for (int jj = 0; jj < 4; ++jj) { ps += o[jj] * ws[jj]; pt += o[jj] * wt[jj]; }
    #pragma unroll
    for (int off = 32; off > 0; off >>= 1) {
        ps += __shfl_xor(ps, off);
        pt += __shfl_xor(pt, off);
    }
    if (lane == 0) { s2[row] = ps; t2[row] = pt; }
}

// ---------------------------------------------------------------------------
// Layer-2 pre-aggregate: softmax(s2,t2) over neighbors, gather enc16 (L2-hot,
// 4 MB), write aggE16 fp16. No ELU (applied after GEMM). Wave per row.
// ---------------------------------------------------------------------------
__global__ void aggregate_l2pre(const _Float16* __restrict__ enc16,
                                const int* __restrict__ cols, const int* __restrict__ cnt,
                                const float* __restrict__ s, const float* __restrict__ t,
                                _Float16* __restrict__ aggE16) {
    const int wid = threadIdx.x >> 6, lane = threadIdx.x & 63;
    const int row = blockIdx.x * 4 + wid;
    const int deg = cnt[row];
    __shared__ float pS[4][64];
    __shared__ int jS[4][64];
    int j = 0;
    float ev = -1e30f;
    if (lane < deg) {
        j = cols[(size_t)row * MAXDEG + lane];
        float z = s[row] + t[j];
        ev = z > 0.0f ? z : ALPHA * z;
    }
    float m = ev;
    #pragma unroll
    for (int off = 32; off > 0; off >>= 1) m = fmaxf(m, __shfl_xor(m, off));
    float ex = (lane < deg) ? __expf(ev - m) : 0.0f;
    float sum = ex;
    #pragma unroll
    for (int off = 32; off > 0; off >>= 1) sum += __shfl_xor(sum, off);
    pS[wid][lane] = ex / sum;
    jS[wid][lane] = j;
    __syncthreads();

    float acc[4] = {};
    const size_t lo = (size_t)lane * 4;
    int d = 0;
    for (; d + 4 <= deg; d += 4) {
        float p0 = pS[wid][d],     p1 = pS[wid][d + 1];
        float p2 = pS[wid][d + 2], p3 = pS[wid][d + 3];
        f16x4 v0 = *(const f16x4*)(enc16 + (size_t)jS[wid][d] * F_HID + lo);
        f16x4 v1 = *(const f16x4*)(enc16 + (size_t)jS[wid][d + 1] * F_HID + lo);
        f16x4 v2 = *(const f16x4*)(enc16 + (size_t)jS[wid][d + 2] * F_HID + lo);
        f16x4 v3 = *(const f16x4*)(enc16 + (size_t)jS[wid][d + 3] * F_HID + lo);
        #pragma unroll
        for (int jj = 0; jj < 4; ++jj)
            acc[jj] += p0 * (float)v0[jj] + p1 * (float)v1[jj]
                     + p2 * (float)v2[jj] + p3 * (float)v3[jj];
    }
    for (; d < deg; ++d) {
        float p = pS[wid][d];
        f16x4 w = *(const f16x4*)(enc16 + (size_t)jS[wid][d] * F_HID + lo);
        #pragma unroll
        for (int jj = 0; jj < 4; ++jj) acc[jj] += p * (float)w[jj];
    }
    f16x4 h;
    #pragma unroll
    for (int jj = 0; jj < 4; ++jj) h[jj] = (_Float16)acc[jj];
    *(f16x4*)(aggE16 + (size_t)row * F_HID + lo) = h;
}

// ---------------------------------------------------------------------------
// GEMM2e: dec[8192,512] f32 = elu( aggE16[8192,256] @ W2 ), B^T layout.
// BM=128, BN=64; B panel resident in LDS; NT f32 stores.
// ---------------------------------------------------------------------------
__global__ __launch_bounds__(256)
void gemm2e(const _Float16* __restrict__ A, const _Float16* __restrict__ BT,
            float* __restrict__ C) {
    const int LDT = 72, LDB = 264;
    __shared__ _Float16 As[128 * LDT];
    __shared__ _Float16 Bs[64 * LDB];
    const int tid = threadIdx.x;
    const int wid = tid >> 6, lane = tid & 63;
    const int brow = (blockIdx.x >> 3) * 128;
    const int bcol = (blockIdx.x & 7) * 64;
    const int wr = (wid >> 1) * 64, wc = (wid & 1) * 32;

    #pragma unroll
    for (int i = 0; i < 8; ++i) {
        int id = tid + i * 256;
        int r = id >> 5, kc = (id & 31) * 8;
        *(f16x8*)&Bs[r * LDB + kc] = *(const f16x8*)&BT[(size_t)(bcol + r) * F_HID + kc];
    }

    f32x4 acc[4][2];
    #pragma unroll
    for (int m = 0; m < 4; ++m)
        #pragma unroll
        for (int n = 0; n < 2; ++n) acc[m][n] = f32x4{0.f, 0.f, 0.f, 0.f};

    for (int k0 = 0; k0 < F_HID; k0 += 64) {
        #pragma unroll
        for (int i = 0; i < 4; ++i) {
            int id = tid + i * 256;
            int r = id >> 3, kc = (id & 7) * 8;
            *(f16x8*)&As[r * LDT + kc] = *(const f16x8*)&A[(size_t)(brow + r) * F_HID + k0 + kc];
        }
        __syncthreads();
        #pragma unroll
        for (int ks = 0; ks < 2; ++ks) {
            const int kb = ks * 32 + (lane >> 4) * 8;
            f16x8 af[4], bfr[2];
            #pragma unroll
            for (int m = 0; m < 4; ++m)
                af[m] = *(const f16x8*)&As[(wr + m * 16 + (lane & 15)) * LDT + kb];
            #pragma unroll
            for (int n = 0; n < 2; ++n)
                bfr[n] = *(const f16x8*)&Bs[(wc + n * 16 + (lane & 15)) * LDB + k0 + kb];
            #pragma unroll
            for (int m = 0; m < 4; ++m)
                #pragma unroll
                for (int n = 0; n < 2; ++n)
                    acc[m][n] = __builtin_amdgcn_mfma_f32_16x16x32_f16(
                        af[m], bfr[n], acc[m][n], 0, 0, 0);
        }
        __syncthreads();
    }
    #pragma unroll
    for (int m = 0; m < 4; ++m)
        #pragma unroll
        for (int n = 0; n < 2; ++n) {
            int row = brow + wr + m * 16 + ((lane >> 4) << 2);
            int col = bcol + wc + n * 16 + (lane & 15);
            #pragma unroll
            for (int j = 0; j < 4; ++j) {
                float v = acc[m][n][j];
                float e = v > 0.0f ? v : (__expf(v) - 1.0f);
                __builtin_nontemporal_store(e, &C[(size_t)(row + j) * F_IN + col]);
            }
        }
}

// ---------------------------------------------------------------------------
extern "C" void kernel_launch(void* const* d_in, const int* in_sizes, int n_in,
                              void* d_out, int out_size, void* d_ws, size_t ws_size,
                              hipStream_t stream) {
    (void)in_sizes; (void)n_in; (void)out_size; (void)ws_size;
    const float* x   = (const float*)d_in[0];
    const float* adj = (const float*)d_in[1];
    const float* W1  = (const float*)d_in[2];
    const float* a1  = (const float*)d_in[3];
    const float* W2  = (const float*)d_in[4];
    const float* a2  = (const float*)d_in[5];

    float* dec = (float*)d_out;                           // [8192, 512] f32
    float* enc = dec + (size_t)N_NODES * F_IN;            // [8192, 256] f32

    int*      cols   = (int*)d_ws;                        // 8192*64
    int*      cnt    = cols + (size_t)N_NODES * MAXDEG;   // 8192
    float*    s1     = (float*)(cnt + N_NODES);           // 8192
    float*    t1     = s1 + N_NODES;                      // 8192
    float*    s2     = t1 + N_NODES;                      // 8192
    float*    t2     = s2 + N_NODES;                      // 8192
    float*    w2s    = t2 + N_NODES;                      // 256
    float*    w2t    = w2s + F_HID;                       // 256
    _Float16* Wh1    = (_Float16*)(w2t + F_HID);          // 8192*256 fp16
    _Float16* enc16  = Wh1 + (size_t)N_NODES * F_HID;     // 8192*256 fp16
    _Float16* aggE16 = enc16 + (size_t)N_NODES * F_HID;   // 8192*256 fp16
    _Float16* W1T    = aggE16 + (size_t)N_NODES * F_HID;  // 256*512 fp16
    _Float16* W2T    = W1T + (size_t)F_HID * F_IN;        // 512*256 fp16

    // 1. W transposes + zero s1/t1 + w2s/w2t = W2 @ a2 halves
    conv_WT<<<260, 256, 0, stream>>>(W1, W2, W1T, W2T, a2, w2s, w2t, s1);

    // 2. csr scan (HBM) overlapped with layer-1 GEMM + s1/t1 epilogue
    csr_and_gemm1<<<2560, 256, 0, stream>>>(adj, cols, cnt, x, W1T, Wh1, a1, s1, t1);

    // 3. layer-1 attention -> enc, enc16; epilogue s2/t2
    aggregate_l1<<<N_NODES / 4, 256, 0, stream>>>(Wh1, cols, cnt, s1, t1,
                                                  w2s, w2t, enc, enc16, s2, t2);

    // 4. layer-2 aggregate in input space (linearity): aggE = att2 @ enc
    aggregate_l2pre<<<N_NODES / 4, 256, 0, stream>>>(enc16, cols, cnt, s2, t2, aggE16);

    // 5. dec = elu(aggE @ W2)
    gemm2e<<<512, 256, 0, stream>>>(aggE16, W2T, dec);
}